// Round 1
// baseline (600.729 us; speedup 1.0000x reference)
//
#include <hip/hip_runtime.h>
#include <hip/hip_bf16.h>

#define N_NODES 50000
#define N_EDGES 800000
#define DIM 64
#define NB 391      // dst buckets of 128 nodes: ceil(50000/128)
#define NBLK 128    // blocks in bucketize pass
#define CHUNK 6250  // N_EDGES / NBLK (exact)
#define CAP 4096    // LDS staging capacity per bucket segment (avg ~2048)

// ---------- helpers ----------
__device__ __forceinline__ float bf2f(unsigned short u) {
  return __uint_as_float(((unsigned int)u) << 16);
}
__device__ __forceinline__ unsigned short f2bf(float f) {
  unsigned int x = __float_as_uint(f);
  unsigned int r = (x + 0x7fffu + ((x >> 16) & 1u)) >> 16;  // RNE
  return (unsigned short)r;
}

// ---------- dtype detection (flags[0]=bf16 inputs, flags[1]=int64 indices) ----------
__global__ void k_detect(const unsigned short* __restrict__ feat,
                         const unsigned int* __restrict__ eidx,
                         int* __restrict__ flags) {
  int lane = threadIdx.x;  // 64 threads
  float v = bf2f(feat[2 * lane]);
  bool big = !(fabsf(v) < 1000.0f);
  unsigned long long bb = __ballot(big);
  unsigned int w = eidx[2 * lane + 1];
  unsigned long long bz = __ballot(w == 0u);
  if (lane == 0) {
    flags[0] = (__popcll(bb) < 8) ? 1 : 0;
    flags[1] = (__popcll(bz) == 64) ? 1 : 0;
  }
}

__device__ __forceinline__ int eidx_at(const int* __restrict__ p, int k, int i64) {
  return p[i64 ? (k << 1) : k];
}

// ---------- generalized scan (n <= 65536) ----------
__global__ void k_scan1(const int* __restrict__ in, int* __restrict__ out,
                        int* __restrict__ bsum, int n) {
  __shared__ int sm[256];
  int t = threadIdx.x, b = blockIdx.x, i = b * 256 + t;
  int v = (i < n) ? in[i] : 0;
  sm[t] = v;
  __syncthreads();
  for (int off = 1; off < 256; off <<= 1) {
    int x = (t >= off) ? sm[t - off] : 0;
    __syncthreads();
    sm[t] += x;
    __syncthreads();
  }
  if (i < n) out[i] = sm[t] - v;
  if (t == 255) bsum[b] = sm[t];
}

__global__ void k_scan2(int* __restrict__ bsum, int nb) {
  __shared__ int sm[256];
  int t = threadIdx.x;
  int v = (t < nb) ? bsum[t] : 0;
  sm[t] = v;
  __syncthreads();
  for (int off = 1; off < 256; off <<= 1) {
    int x = (t >= off) ? sm[t - off] : 0;
    __syncthreads();
    sm[t] += x;
    __syncthreads();
  }
  if (t < nb) bsum[t] = sm[t] - v;
}

__global__ void k_scan3(int* __restrict__ out, const int* __restrict__ bsum, int n) {
  int t = threadIdx.x, b = blockIdx.x, i = b * 256 + t;
  if (i < n) out[i] += bsum[b];
}

// ---------- bucketed CSR build ----------
__global__ __launch_bounds__(256) void k_hist1(const int* __restrict__ eidx,
                                               const int* __restrict__ flags,
                                               int* __restrict__ hist) {
  __shared__ int h[NB];
  int t = threadIdx.x, b = blockIdx.x;
  for (int i = t; i < NB; i += 256) h[i] = 0;
  __syncthreads();
  int i64 = flags[1];
  int lo = b * CHUNK;
  for (int i = t; i < CHUNK; i += 256) {
    int d = eidx_at(eidx, N_EDGES + lo + i, i64);
    atomicAdd(&h[d >> 7], 1);
  }
  __syncthreads();
  for (int i = t; i < NB; i += 256) hist[i * NBLK + b] = h[i];
}

__global__ __launch_bounds__(256) void k_scatter(const int* __restrict__ eidx,
                                                 const int* __restrict__ flags,
                                                 const int* __restrict__ hscan,
                                                 int2* __restrict__ ebuf) {
  __shared__ int cur[NB];
  int t = threadIdx.x, b = blockIdx.x;
  for (int i = t; i < NB; i += 256) cur[i] = hscan[i * NBLK + b];
  __syncthreads();
  int i64 = flags[1];
  int lo = b * CHUNK;
  for (int i = t; i < CHUNK; i += 256) {
    int d = eidx_at(eidx, N_EDGES + lo + i, i64);
    int s = eidx_at(eidx, lo + i, i64);
    int pos = atomicAdd(&cur[d >> 7], 1);
    ebuf[pos] = make_int2(s, d);
  }
}

// fused: per-bucket degree histogram + local scan -> rowp, then LDS-staged
// CSR placement (bucket segments are dst-contiguous).
__global__ __launch_bounds__(256) void k_place(const int2* __restrict__ ebuf,
                                               const int* __restrict__ hscan,
                                               int* __restrict__ rowp,
                                               int* __restrict__ csr) {
  __shared__ int hcnt[128];
  __shared__ int sm[128];
  __shared__ int cur[128];
  __shared__ int lcsr[CAP];
  int t = threadIdx.x, b = blockIdx.x;
  int lo = hscan[b * NBLK];
  int hi = (b + 1 < NB) ? hscan[(b + 1) * NBLK] : N_EDGES;
  if (t < 128) hcnt[t] = 0;
  __syncthreads();
  for (int i = lo + t; i < hi; i += 256) atomicAdd(&hcnt[ebuf[i].y & 127], 1);
  __syncthreads();
  int v = (t < 128) ? hcnt[t] : 0;
  if (t < 128) sm[t] = v;
  __syncthreads();
  for (int off = 1; off < 128; off <<= 1) {
    int x = (t < 128 && t >= off) ? sm[t - off] : 0;
    __syncthreads();
    if (t < 128) sm[t] += x;
    __syncthreads();
  }
  int d0 = b * 128;
  if (t < 128) {
    int excl = sm[t] - v;  // exclusive local prefix
    cur[t] = excl;
    int d = d0 + t;
    if (d < N_NODES) rowp[d] = lo + excl;
  }
  if (b == NB - 1 && t == 0) rowp[N_NODES] = N_EDGES;
  __syncthreads();
  int seg_sz = hi - lo;
  if (seg_sz <= CAP) {
    for (int i = lo + t; i < hi; i += 256) {
      int2 pr = ebuf[i];
      int pos = atomicAdd(&cur[pr.y & 127], 1);
      lcsr[pos] = pr.x;
    }
    __syncthreads();
    for (int i = t; i < seg_sz; i += 256) csr[lo + i] = lcsr[i];
  } else {  // overflow fallback
    for (int i = lo + t; i < hi; i += 256) {
      int2 pr = ebuf[i];
      int pos = atomicAdd(&cur[pr.y & 127], 1);
      csr[lo + pos] = pr.x;
    }
  }
}

// ---------- h = x@W (h stored bf16), s_src = h@a_s, s_dst = h@a_d (fp32) ----------
// R10: two rows per iteration -> two independent FMA chains per wave (the
// single-acc 64-FMA chain was 256 serial cycles/row with only ~4 waves/SIMD
// of TLP to hide it).
__global__ __launch_bounds__(256) void k_gemm(
    const void* __restrict__ xv, int x_raw, const void* __restrict__ Wv,
    const void* __restrict__ asv, const void* __restrict__ adv, int head,
    const int* __restrict__ flags, unsigned short* __restrict__ hb,
    float* __restrict__ ss, float* __restrict__ sd) {
  const int bf = flags[0];
  const int lane = threadIdx.x & 63;
  const int wid = blockIdx.x * (blockDim.x >> 6) + (threadIdx.x >> 6);
  const int nw = gridDim.x * (blockDim.x >> 6);
  float wcol[DIM];
  float a_s, a_d;
  if (bf) {
    const unsigned short* W = (const unsigned short*)Wv + head * DIM * DIM;
    const unsigned short* pa = (const unsigned short*)asv + head * DIM;
    const unsigned short* pd = (const unsigned short*)adv + head * DIM;
#pragma unroll
    for (int k = 0; k < DIM; ++k) wcol[k] = bf2f(W[k * DIM + lane]);
    a_s = bf2f(pa[lane]); a_d = bf2f(pd[lane]);
  } else {
    const float* W = (const float*)Wv + head * DIM * DIM;
    const float* pa = (const float*)asv + head * DIM;
    const float* pd = (const float*)adv + head * DIM;
#pragma unroll
    for (int k = 0; k < DIM; ++k) wcol[k] = W[k * DIM + lane];
    a_s = pa[lane]; a_d = pd[lane];
  }
  const int raw_bf = x_raw && bf;
  for (int row = wid; row < N_NODES; row += 2 * nw) {
    const int row1 = row + nw;
    const int h2 = (row1 < N_NODES);
    float acc0 = 0.f, acc1 = 0.f;
    if (raw_bf) {
      const ushort4* x0 = (const ushort4*)((const unsigned short*)xv + row * DIM);
      const ushort4* x1 = (const ushort4*)((const unsigned short*)xv + (h2 ? row1 : row) * DIM);
#pragma unroll
      for (int q = 0; q < DIM / 4; ++q) {
        ushort4 u0 = x0[q];
        ushort4 u1 = x1[q];
        acc0 = fmaf(bf2f(u0.x), wcol[4 * q + 0], acc0);
        acc1 = fmaf(bf2f(u1.x), wcol[4 * q + 0], acc1);
        acc0 = fmaf(bf2f(u0.y), wcol[4 * q + 1], acc0);
        acc1 = fmaf(bf2f(u1.y), wcol[4 * q + 1], acc1);
        acc0 = fmaf(bf2f(u0.z), wcol[4 * q + 2], acc0);
        acc1 = fmaf(bf2f(u1.z), wcol[4 * q + 2], acc1);
        acc0 = fmaf(bf2f(u0.w), wcol[4 * q + 3], acc0);
        acc1 = fmaf(bf2f(u1.w), wcol[4 * q + 3], acc1);
      }
    } else {
      const float4* x0 = (const float4*)((const float*)xv + row * DIM);
      const float4* x1 = (const float4*)((const float*)xv + (h2 ? row1 : row) * DIM);
#pragma unroll
      for (int q = 0; q < DIM / 4; ++q) {
        float4 f0 = x0[q];
        float4 f1 = x1[q];
        acc0 = fmaf(f0.x, wcol[4 * q + 0], acc0);
        acc1 = fmaf(f1.x, wcol[4 * q + 0], acc1);
        acc0 = fmaf(f0.y, wcol[4 * q + 1], acc0);
        acc1 = fmaf(f1.y, wcol[4 * q + 1], acc1);
        acc0 = fmaf(f0.z, wcol[4 * q + 2], acc0);
        acc1 = fmaf(f1.z, wcol[4 * q + 2], acc1);
        acc0 = fmaf(f0.w, wcol[4 * q + 3], acc0);
        acc1 = fmaf(f1.w, wcol[4 * q + 3], acc1);
      }
    }
    hb[row * DIM + lane] = f2bf(acc0);
    float u0 = acc0 * a_s, v0 = acc0 * a_d;
    float u1 = acc1 * a_s, v1 = acc1 * a_d;
#pragma unroll
    for (int off = 32; off > 0; off >>= 1) {
      u0 += __shfl_xor(u0, off);
      v0 += __shfl_xor(v0, off);
      u1 += __shfl_xor(u1, off);
      v1 += __shfl_xor(v1, off);
    }
    if (lane == 0) { ss[row] = u0; sd[row] = v0; }
    if (h2) {
      hb[row1 * DIM + lane] = f2bf(acc1);
      if (lane == 0) { ss[row1] = u1; sd[row1] = v1; }
    }
  }
}

// ---------- per-dst-node softmax aggregation (one wave per node, R6/R8 proven) ----------
// quad-gather: quarter-wave (16 lanes) per edge, each lane loads ushort4
// (4 cols, 8 B) -> one full 128 B h-row per quarter-wave, 4 edges & 512 B
// per load instruction. Softmax without max-subtraction (shift-invariant;
// scores are O(10) so fp32 exp is safe — verified bit-identical absmax in R9).
// R10: z-reduction moved AFTER quad_accum in the deg<=64 path — z is only
// needed in the epilogue, and the 6 dependent shuffle+adds were delaying the
// lps write (and hence every h-row gather) by ~60 cy per node.
__device__ __forceinline__ void quad_accum(const unsigned short* __restrict__ hb,
                                           const int2* __restrict__ lps, int cl,
                                           int quarter, int c16, float4& acc) {
  const int quads = (cl + 3) >> 2;
#pragma unroll 4
  for (int tt = 0; tt < quads; ++tt) {
    int j = 4 * tt + quarter;  // tail entries have p=0,s=0 -> contribute 0
    int2 pv = lps[j];          // LDS broadcast within quarter-wave
    float pj = __int_as_float(pv.x);
    int sj = pv.y;
    ushort4 hv = *(const ushort4*)(hb + sj * DIM + 4 * c16);
    acc.x = fmaf(pj, bf2f(hv.x), acc.x);
    acc.y = fmaf(pj, bf2f(hv.y), acc.y);
    acc.z = fmaf(pj, bf2f(hv.z), acc.z);
    acc.w = fmaf(pj, bf2f(hv.w), acc.w);
  }
}

__global__ __launch_bounds__(256) void k_agg(
    const unsigned short* __restrict__ hb, const float* __restrict__ ss,
    const float* __restrict__ sd, const int* __restrict__ rowp,
    const int* __restrict__ csr, float* __restrict__ out_f,
    void* __restrict__ out_final, const int* __restrict__ flags,
    int do_elu, int is_final) {
  __shared__ __align__(16) int2 lps[4][64];  // {p bits, src}
  const int lane = threadIdx.x & 63;
  const int quarter = lane >> 4;
  const int c16 = lane & 15;  // this lane covers cols 4*c16 .. 4*c16+3
  const int w = threadIdx.x >> 6;
  const int node = blockIdx.x * 4 + w;
  const int base = rowp[node];
  const int deg = rowp[node + 1] - base;
  const float sdn = sd[node];

  float4 acc = {0.f, 0.f, 0.f, 0.f};
  float z;
  if (deg <= 64) {
    int s = 0;
    float p = 0.f;
    if (lane < deg) {
      s = csr[base + lane];
      float t = ss[s] + sdn;
      t = (t >= 0.f) ? t : 0.2f * t;
      p = __expf(t);  // no max-subtraction needed (shift-invariant, scores O(10))
    }
    lps[w][lane] = make_int2(__float_as_int(p), s);
    z = p;
    __builtin_amdgcn_wave_barrier();
    quad_accum(hb, &lps[w][0], deg, quarter, c16, acc);
    // z-reduce after the gathers are issued; overlaps with acc combine below
#pragma unroll
    for (int off = 32; off > 0; off >>= 1) z += __shfl_xor(z, off);
  } else {
    z = 0.f;
    for (int c = 0; c < deg; c += 64) {
      int j = c + lane;
      float p = 0.f; int s = 0;
      if (j < deg) {
        s = csr[base + j];
        float sc = ss[s] + sdn;
        sc = (sc >= 0.f) ? sc : 0.2f * sc;
        p = __expf(sc);
      }
      lps[w][lane] = make_int2(__float_as_int(p), s);
      __builtin_amdgcn_wave_barrier();
      z += p;
      const int cl = (deg - c < 64) ? (deg - c) : 64;
      quad_accum(hb, &lps[w][0], cl, quarter, c16, acc);
      __builtin_amdgcn_wave_barrier();
    }
#pragma unroll
    for (int off = 32; off > 0; off >>= 1) z += __shfl_xor(z, off);
  }

  // combine the four quarter-wave partial sums (same cols, disjoint edges)
  acc.x += __shfl_xor(acc.x, 16);
  acc.y += __shfl_xor(acc.y, 16);
  acc.z += __shfl_xor(acc.z, 16);
  acc.w += __shfl_xor(acc.w, 16);
  acc.x += __shfl_xor(acc.x, 32);
  acc.y += __shfl_xor(acc.y, 32);
  acc.z += __shfl_xor(acc.z, 32);
  acc.w += __shfl_xor(acc.w, 32);

  float inv = 1.f / (z + 1e-16f);  // deg==0 -> 0, matches reference
  float ox = acc.x * inv, oy = acc.y * inv;
  float oz = acc.z * inv, ow = acc.w * inv;
  if (do_elu) {
    ox = (ox > 0.f) ? ox : expm1f(ox);
    oy = (oy > 0.f) ? oy : expm1f(oy);
    oz = (oz > 0.f) ? oz : expm1f(oz);
    ow = (ow > 0.f) ? ow : expm1f(ow);
  }
  if (quarter == 0) {
    int idx = node * DIM + 4 * c16;
    if (is_final) {
      if (flags[0]) {
        ushort4 o4 = {f2bf(ox), f2bf(oy), f2bf(oz), f2bf(ow)};
        *(ushort4*)((unsigned short*)out_final + idx) = o4;
      } else {
        float4 o4 = {ox, oy, oz, ow};
        *(float4*)((float*)out_final + idx) = o4;
      }
    } else {
      float4 o4 = {ox, oy, oz, ow};
      *(float4*)(out_f + idx) = o4;
    }
  }
}

// ---------- launch ----------
extern "C" void kernel_launch(void* const* d_in, const int* in_sizes, int n_in,
                              void* d_out, int out_size, void* d_ws, size_t ws_size,
                              hipStream_t stream) {
  const void* feat = d_in[0];
  const int* eidx = (const int*)d_in[1];

  float* bufA = (float*)d_ws;                                    // N*64 f32
  float* bufB = bufA + N_NODES * DIM;                            // N*64 f32
  unsigned short* hb = (unsigned short*)(bufB + N_NODES * DIM);  // N*64 bf16
  int2* ebuf = (int2*)(hb + N_NODES * DIM);                      // E int2
  float* ssrc = (float*)(ebuf + N_EDGES);                        // N
  float* sdst = ssrc + N_NODES;                                  // N
  int* rowp = (int*)(sdst + N_NODES);                            // N+1
  int* csr  = rowp + N_NODES + 1;                                // E
  int* hist = csr + N_EDGES;                                     // NB*NBLK
  int* hscan = hist + NB * NBLK;                                 // NB*NBLK
  int* bsum = hscan + NB * NBLK;                                 // 256
  int* flags = bsum + 256;                                       // 2

  const int NH = NB * NBLK;                 // 50048
  const int SBH = (NH + 255) / 256;         // 196

  k_detect<<<1, 64, 0, stream>>>((const unsigned short*)feat,
                                 (const unsigned int*)eidx, flags);
  k_hist1<<<NBLK, 256, 0, stream>>>(eidx, flags, hist);
  k_scan1<<<SBH, 256, 0, stream>>>(hist, hscan, bsum, NH);
  k_scan2<<<1, 256, 0, stream>>>(bsum, SBH);
  k_scan3<<<SBH, 256, 0, stream>>>(hscan, bsum, NH);
  k_scatter<<<NBLK, 256, 0, stream>>>(eidx, flags, hscan, ebuf);
  k_place<<<NB, 256, 0, stream>>>(ebuf, hscan, rowp, csr);

  const void* xcur = feat;
  int x_raw = 1;
  float* nxt = bufA;
  float* other = bufB;
  for (int i = 0; i < 8; ++i) {
    const void* Wb = (i < 4) ? d_in[2] : d_in[5];
    const void* ab = (i < 4) ? d_in[3] : d_in[6];
    const void* db = (i < 4) ? d_in[4] : d_in[7];
    int head = i & 3;
    k_gemm<<<1024, 256, 0, stream>>>(xcur, x_raw, Wb, ab, db, head, flags,
                                     hb, ssrc, sdst);
    int elu = (i == 3 || i == 7) ? 1 : 0;
    int fin = (i == 7) ? 1 : 0;
    k_agg<<<N_NODES / 4, 256, 0, stream>>>(hb, ssrc, sdst, rowp, csr, nxt,
                                           d_out, flags, elu, fin);
    xcur = nxt; x_raw = 0;
    float* t = nxt; nxt = other; other = t;
  }
}

// Round 4
// 405.717 us; speedup vs baseline: 1.4807x; 1.4807x over previous
//
#include <hip/hip_runtime.h>
#include <hip/hip_bf16.h>

#define N_NODES 50000
#define N_EDGES 800000
#define DIM 64
#define NB 391      // dst buckets of 128 nodes: ceil(50000/128)
#define NBLK 128    // blocks in bucketize pass
#define CHUNK 6250  // N_EDGES / NBLK (exact)
#define CAP 4096    // LDS staging capacity per bucket segment (avg ~2048)
#define NTILES 3125 // 50000 / 16 row-tiles (exact)

typedef __attribute__((ext_vector_type(8))) short bf16x8;
typedef __attribute__((ext_vector_type(4))) float f32x4;

// ---------- helpers ----------
__device__ __forceinline__ float bf2f(unsigned short u) {
  return __uint_as_float(((unsigned int)u) << 16);
}
__device__ __forceinline__ unsigned short f2bf(float f) {
  unsigned int x = __float_as_uint(f);
  unsigned int r = (x + 0x7fffu + ((x >> 16) & 1u)) >> 16;  // RNE
  return (unsigned short)r;
}

// ---------- dtype detection (flags[0]=bf16 inputs, flags[1]=int64 indices) ----------
__global__ void k_detect(const unsigned short* __restrict__ feat,
                         const unsigned int* __restrict__ eidx,
                         int* __restrict__ flags) {
  int lane = threadIdx.x;  // 64 threads
  float v = bf2f(feat[2 * lane]);
  bool big = !(fabsf(v) < 1000.0f);
  unsigned long long bb = __ballot(big);
  unsigned int w = eidx[2 * lane + 1];
  unsigned long long bz = __ballot(w == 0u);
  if (lane == 0) {
    flags[0] = (__popcll(bb) < 8) ? 1 : 0;
    flags[1] = (__popcll(bz) == 64) ? 1 : 0;
  }
}

__device__ __forceinline__ int eidx_at(const int* __restrict__ p, int k, int i64) {
  return p[i64 ? (k << 1) : k];
}

// ---------- generalized scan (n <= 65536) ----------
__global__ void k_scan1(const int* __restrict__ in, int* __restrict__ out,
                        int* __restrict__ bsum, int n) {
  __shared__ int sm[256];
  int t = threadIdx.x, b = blockIdx.x, i = b * 256 + t;
  int v = (i < n) ? in[i] : 0;
  sm[t] = v;
  __syncthreads();
  for (int off = 1; off < 256; off <<= 1) {
    int x = (t >= off) ? sm[t - off] : 0;
    __syncthreads();
    sm[t] += x;
    __syncthreads();
  }
  if (i < n) out[i] = sm[t] - v;
  if (t == 255) bsum[b] = sm[t];
}

__global__ void k_scan2(int* __restrict__ bsum, int nb) {
  __shared__ int sm[256];
  int t = threadIdx.x;
  int v = (t < nb) ? bsum[t] : 0;
  sm[t] = v;
  __syncthreads();
  for (int off = 1; off < 256; off <<= 1) {
    int x = (t >= off) ? sm[t - off] : 0;
    __syncthreads();
    sm[t] += x;
    __syncthreads();
  }
  if (t < nb) bsum[t] = sm[t] - v;
}

__global__ void k_scan3(int* __restrict__ out, const int* __restrict__ bsum, int n) {
  int t = threadIdx.x, b = blockIdx.x, i = b * 256 + t;
  if (i < n) out[i] += bsum[b];
}

// ---------- bucketed CSR build ----------
__global__ __launch_bounds__(256) void k_hist1(const int* __restrict__ eidx,
                                               const int* __restrict__ flags,
                                               int* __restrict__ hist) {
  __shared__ int h[NB];
  int t = threadIdx.x, b = blockIdx.x;
  for (int i = t; i < NB; i += 256) h[i] = 0;
  __syncthreads();
  int i64 = flags[1];
  int lo = b * CHUNK;
  for (int i = t; i < CHUNK; i += 256) {
    int d = eidx_at(eidx, N_EDGES + lo + i, i64);
    atomicAdd(&h[d >> 7], 1);
  }
  __syncthreads();
  for (int i = t; i < NB; i += 256) hist[i * NBLK + b] = h[i];
}

__global__ __launch_bounds__(256) void k_scatter(const int* __restrict__ eidx,
                                                 const int* __restrict__ flags,
                                                 const int* __restrict__ hscan,
                                                 int2* __restrict__ ebuf) {
  __shared__ int cur[NB];
  int t = threadIdx.x, b = blockIdx.x;
  for (int i = t; i < NB; i += 256) cur[i] = hscan[i * NBLK + b];
  __syncthreads();
  int i64 = flags[1];
  int lo = b * CHUNK;
  for (int i = t; i < CHUNK; i += 256) {
    int d = eidx_at(eidx, N_EDGES + lo + i, i64);
    int s = eidx_at(eidx, lo + i, i64);
    int pos = atomicAdd(&cur[d >> 7], 1);
    ebuf[pos] = make_int2(s, d);
  }
}

// fused: per-bucket degree histogram + local scan -> rowp, then LDS-staged
// CSR placement (bucket segments are dst-contiguous).
__global__ __launch_bounds__(256) void k_place(const int2* __restrict__ ebuf,
                                               const int* __restrict__ hscan,
                                               int* __restrict__ rowp,
                                               int* __restrict__ csr) {
  __shared__ int hcnt[128];
  __shared__ int sm[128];
  __shared__ int cur[128];
  __shared__ int lcsr[CAP];
  int t = threadIdx.x, b = blockIdx.x;
  int lo = hscan[b * NBLK];
  int hi = (b + 1 < NB) ? hscan[(b + 1) * NBLK] : N_EDGES;
  if (t < 128) hcnt[t] = 0;
  __syncthreads();
  for (int i = lo + t; i < hi; i += 256) atomicAdd(&hcnt[ebuf[i].y & 127], 1);
  __syncthreads();
  int v = (t < 128) ? hcnt[t] : 0;
  if (t < 128) sm[t] = v;
  __syncthreads();
  for (int off = 1; off < 128; off <<= 1) {
    int x = (t < 128 && t >= off) ? sm[t - off] : 0;
    __syncthreads();
    if (t < 128) sm[t] += x;
    __syncthreads();
  }
  int d0 = b * 128;
  if (t < 128) {
    int excl = sm[t] - v;  // exclusive local prefix
    cur[t] = excl;
    int d = d0 + t;
    if (d < N_NODES) rowp[d] = lo + excl;
  }
  if (b == NB - 1 && t == 0) rowp[N_NODES] = N_EDGES;
  __syncthreads();
  int seg_sz = hi - lo;
  if (seg_sz <= CAP) {
    for (int i = lo + t; i < hi; i += 256) {
      int2 pr = ebuf[i];
      int pos = atomicAdd(&cur[pr.y & 127], 1);
      lcsr[pos] = pr.x;
    }
    __syncthreads();
    for (int i = t; i < seg_sz; i += 256) csr[lo + i] = lcsr[i];
  } else {  // overflow fallback
    for (int i = lo + t; i < hi; i += 256) {
      int2 pr = ebuf[i];
      int pos = atomicAdd(&cur[pr.y & 127], 1);
      csr[lo + pos] = pr.x;
    }
  }
}

// ---------- MFMA h = x@W  (R11 rewrite) ----------
// Old VALU k_gemm was 46 us/dispatch, VALUBusy 17%, latency-bound: wcol[64]
// register-resident W starved the loader of VGPRs and occupancy. New: one
// wave computes a 16x64 tile with mfma_f32_16x16x32_bf16 (2 K-steps x 4
// col-blocks). W lives in B-fragments (loaded once/wave). fp32 x is split
// hi/lo bf16 (2 MFMAs) for ~fp32 accuracy. A and B fragment loaders share
// the same k<->(lane-group,elem) map, so any k-grouping mismatch with HW
// permutes the k-sum identically on both operands and cancels.
// D layout (m89-verified): col = lane&15, row = (lane>>4)*4 + reg.
__global__ __launch_bounds__(256) void k_gemm(
    const void* __restrict__ xv, int x_raw, const void* __restrict__ Wv,
    const void* __restrict__ asv, const void* __restrict__ adv, int head,
    const int* __restrict__ flags, unsigned short* __restrict__ hb,
    float* __restrict__ ss, float* __restrict__ sd) {
  const int bf = flags[0];
  const int lane = threadIdx.x & 63;
  const int wtile = blockIdx.x * 4 + (threadIdx.x >> 6);
  if (wtile >= NTILES) return;
  const int r16 = lane & 15;  // A-row / B-col / D-col within 16
  const int g4 = lane >> 4;   // k-group (8 elems each)
  const int row0 = wtile * 16;

  // ---- B fragments from W (and lo-split when W is fp32)
  bf16x8 Bh[4][2];
  bf16x8 Bl[4][2];
  if (bf) {
    const unsigned short* W = (const unsigned short*)Wv + head * DIM * DIM;
#pragma unroll
    for (int cb = 0; cb < 4; ++cb)
#pragma unroll
      for (int ks = 0; ks < 2; ++ks)
#pragma unroll
        for (int j = 0; j < 8; ++j)
          Bh[cb][ks][j] = (short)W[(32 * ks + 8 * g4 + j) * DIM + 16 * cb + r16];
  } else {
    const float* W = (const float*)Wv + head * DIM * DIM;
#pragma unroll
    for (int cb = 0; cb < 4; ++cb)
#pragma unroll
      for (int ks = 0; ks < 2; ++ks)
#pragma unroll
        for (int j = 0; j < 8; ++j) {
          float w = W[(32 * ks + 8 * g4 + j) * DIM + 16 * cb + r16];
          unsigned short hu = f2bf(w);
          Bh[cb][ks][j] = (short)hu;
          Bl[cb][ks][j] = (short)f2bf(w - bf2f(hu));
        }
  }

  // ---- A fragments from x (row = row0 + r16, k = 32*ks + 8*g4 + j)
  const int a_bf = x_raw && bf;  // layer-0 bf16 features: direct, 1 term
  bf16x8 Ah[2], Al[2];
  if (a_bf) {
    const unsigned short* xp = (const unsigned short*)xv + (row0 + r16) * DIM + 8 * g4;
#pragma unroll
    for (int ks = 0; ks < 2; ++ks)
      Ah[ks] = *(const bf16x8*)(xp + 32 * ks);
  } else {
    const float* xp = (const float*)xv + (row0 + r16) * DIM + 8 * g4;
#pragma unroll
    for (int ks = 0; ks < 2; ++ks) {
      float4 f0 = *(const float4*)(xp + 32 * ks);
      float4 f1 = *(const float4*)(xp + 32 * ks + 4);
      float v[8] = {f0.x, f0.y, f0.z, f0.w, f1.x, f1.y, f1.z, f1.w};
#pragma unroll
      for (int j = 0; j < 8; ++j) {
        unsigned short hu = f2bf(v[j]);
        Ah[ks][j] = (short)hu;
        Al[ks][j] = (short)f2bf(v[j] - bf2f(hu));
      }
    }
  }

  // ---- MFMA: acc[cb] = sum over k-steps (+ hi/lo terms)
  f32x4 acc[4];
#pragma unroll
  for (int cb = 0; cb < 4; ++cb) {
    acc[cb] = (f32x4){0.f, 0.f, 0.f, 0.f};
#pragma unroll
    for (int ks = 0; ks < 2; ++ks) {
      acc[cb] = __builtin_amdgcn_mfma_f32_16x16x32_bf16(Ah[ks], Bh[cb][ks], acc[cb], 0, 0, 0);
      if (!a_bf)
        acc[cb] = __builtin_amdgcn_mfma_f32_16x16x32_bf16(Al[ks], Bh[cb][ks], acc[cb], 0, 0, 0);
      if (!bf)
        acc[cb] = __builtin_amdgcn_mfma_f32_16x16x32_bf16(Ah[ks], Bl[cb][ks], acc[cb], 0, 0, 0);
    }
  }

  // ---- attention-vector slices for this lane's columns
  float asl[4], adl[4];
  if (bf) {
    const unsigned short* pa = (const unsigned short*)asv + head * DIM;
    const unsigned short* pd = (const unsigned short*)adv + head * DIM;
#pragma unroll
    for (int cb = 0; cb < 4; ++cb) {
      asl[cb] = bf2f(pa[16 * cb + r16]);
      adl[cb] = bf2f(pd[16 * cb + r16]);
    }
  } else {
    const float* pa = (const float*)asv + head * DIM;
    const float* pd = (const float*)adv + head * DIM;
#pragma unroll
    for (int cb = 0; cb < 4; ++cb) {
      asl[cb] = pa[16 * cb + r16];
      adl[cb] = pd[16 * cb + r16];
    }
  }

  // ---- epilogue: h store (bf16) + score partials from fp32 acc
  float u[4] = {0.f, 0.f, 0.f, 0.f}, vv[4] = {0.f, 0.f, 0.f, 0.f};
#pragma unroll
  for (int cb = 0; cb < 4; ++cb)
#pragma unroll
    for (int reg = 0; reg < 4; ++reg) {
      float hv = acc[cb][reg];
      hb[(row0 + 4 * g4 + reg) * DIM + 16 * cb + r16] = f2bf(hv);
      u[reg] = fmaf(hv, asl[cb], u[reg]);
      vv[reg] = fmaf(hv, adl[cb], vv[reg]);
    }
  // reduce across the 16 lanes holding each row (xor masks stay in-group)
#pragma unroll
  for (int off = 1; off < 16; off <<= 1)
#pragma unroll
    for (int reg = 0; reg < 4; ++reg) {
      u[reg] += __shfl_xor(u[reg], off);
      vv[reg] += __shfl_xor(vv[reg], off);
    }
  if (r16 == 0) {
#pragma unroll
    for (int reg = 0; reg < 4; ++reg) {
      ss[row0 + 4 * g4 + reg] = u[reg];
      sd[row0 + 4 * g4 + reg] = vv[reg];
    }
  }
}

// ---------- per-dst-node softmax aggregation (one wave per node, R6/R8 proven) ----------
// quad-gather: quarter-wave (16 lanes) per edge, each lane loads ushort4
// (4 cols, 8 B) -> one full 128 B h-row per quarter-wave, 4 edges & 512 B
// per load instruction. Softmax without max-subtraction (shift-invariant;
// scores are O(10) so fp32 exp is safe — verified bit-identical absmax in R9).
__device__ __forceinline__ void quad_accum(const unsigned short* __restrict__ hb,
                                           const int2* __restrict__ lps, int cl,
                                           int quarter, int c16, float4& acc) {
  const int quads = (cl + 3) >> 2;
#pragma unroll 4
  for (int tt = 0; tt < quads; ++tt) {
    int j = 4 * tt + quarter;  // tail entries have p=0,s=0 -> contribute 0
    int2 pv = lps[j];          // LDS broadcast within quarter-wave
    float pj = __int_as_float(pv.x);
    int sj = pv.y;
    ushort4 hv = *(const ushort4*)(hb + sj * DIM + 4 * c16);
    acc.x = fmaf(pj, bf2f(hv.x), acc.x);
    acc.y = fmaf(pj, bf2f(hv.y), acc.y);
    acc.z = fmaf(pj, bf2f(hv.z), acc.z);
    acc.w = fmaf(pj, bf2f(hv.w), acc.w);
  }
}

__global__ __launch_bounds__(256) void k_agg(
    const unsigned short* __restrict__ hb, const float* __restrict__ ss,
    const float* __restrict__ sd, const int* __restrict__ rowp,
    const int* __restrict__ csr, float* __restrict__ out_f,
    void* __restrict__ out_final, const int* __restrict__ flags,
    int do_elu, int is_final) {
  __shared__ __align__(16) int2 lps[4][64];  // {p bits, src}
  const int lane = threadIdx.x & 63;
  const int quarter = lane >> 4;
  const int c16 = lane & 15;  // this lane covers cols 4*c16 .. 4*c16+3
  const int w = threadIdx.x >> 6;
  const int node = blockIdx.x * 4 + w;
  const int base = rowp[node];
  const int deg = rowp[node + 1] - base;
  const float sdn = sd[node];

  float4 acc = {0.f, 0.f, 0.f, 0.f};
  float z;
  if (deg <= 64) {
    int s = 0;
    float p = 0.f;
    if (lane < deg) {
      s = csr[base + lane];
      float t = ss[s] + sdn;
      t = (t >= 0.f) ? t : 0.2f * t;
      p = __expf(t);  // no max-subtraction needed (shift-invariant, scores O(10))
    }
    lps[w][lane] = make_int2(__float_as_int(p), s);
    z = p;
    __builtin_amdgcn_wave_barrier();
    quad_accum(hb, &lps[w][0], deg, quarter, c16, acc);
    // z-reduce after the gathers are issued; overlaps with acc combine below
#pragma unroll
    for (int off = 32; off > 0; off >>= 1) z += __shfl_xor(z, off);
  } else {
    z = 0.f;
    for (int c = 0; c < deg; c += 64) {
      int j = c + lane;
      float p = 0.f; int s = 0;
      if (j < deg) {
        s = csr[base + j];
        float sc = ss[s] + sdn;
        sc = (sc >= 0.f) ? sc : 0.2f * sc;
        p = __expf(sc);
      }
      lps[w][lane] = make_int2(__float_as_int(p), s);
      __builtin_amdgcn_wave_barrier();
      z += p;
      const int cl = (deg - c < 64) ? (deg - c) : 64;
      quad_accum(hb, &lps[w][0], cl, quarter, c16, acc);
      __builtin_amdgcn_wave_barrier();
    }
#pragma unroll
    for (int off = 32; off > 0; off >>= 1) z += __shfl_xor(z, off);
  }

  // combine the four quarter-wave partial sums (same cols, disjoint edges)
  acc.x += __shfl_xor(acc.x, 16);
  acc.y += __shfl_xor(acc.y, 16);
  acc.z += __shfl_xor(acc.z, 16);
  acc.w += __shfl_xor(acc.w, 16);
  acc.x += __shfl_xor(acc.x, 32);
  acc.y += __shfl_xor(acc.y, 32);
  acc.z += __shfl_xor(acc.z, 32);
  acc.w += __shfl_xor(acc.w, 32);

  float inv = 1.f / (z + 1e-16f);  // deg==0 -> 0, matches reference
  float ox = acc.x * inv, oy = acc.y * inv;
  float oz = acc.z * inv, ow = acc.w * inv;
  if (do_elu) {
    ox = (ox > 0.f) ? ox : expm1f(ox);
    oy = (oy > 0.f) ? oy : expm1f(oy);
    oz = (oz > 0.f) ? oz : expm1f(oz);
    ow = (ow > 0.f) ? ow : expm1f(ow);
  }
  if (quarter == 0) {
    int idx = node * DIM + 4 * c16;
    if (is_final) {
      if (flags[0]) {
        ushort4 o4 = {f2bf(ox), f2bf(oy), f2bf(oz), f2bf(ow)};
        *(ushort4*)((unsigned short*)out_final + idx) = o4;
      } else {
        float4 o4 = {ox, oy, oz, ow};
        *(float4*)((float*)out_final + idx) = o4;
      }
    } else {
      float4 o4 = {ox, oy, oz, ow};
      *(float4*)(out_f + idx) = o4;
    }
  }
}

// ---------- launch ----------
extern "C" void kernel_launch(void* const* d_in, const int* in_sizes, int n_in,
                              void* d_out, int out_size, void* d_ws, size_t ws_size,
                              hipStream_t stream) {
  const void* feat = d_in[0];
  const int* eidx = (const int*)d_in[1];

  float* bufA = (float*)d_ws;                                    // N*64 f32
  float* bufB = bufA + N_NODES * DIM;                            // N*64 f32
  unsigned short* hb = (unsigned short*)(bufB + N_NODES * DIM);  // N*64 bf16
  int2* ebuf = (int2*)(hb + N_NODES * DIM);                      // E int2
  float* ssrc = (float*)(ebuf + N_EDGES);                        // N
  float* sdst = ssrc + N_NODES;                                  // N
  int* rowp = (int*)(sdst + N_NODES);                            // N+1
  int* csr  = rowp + N_NODES + 1;                                // E
  int* hist = csr + N_EDGES;                                     // NB*NBLK
  int* hscan = hist + NB * NBLK;                                 // NB*NBLK
  int* bsum = hscan + NB * NBLK;                                 // 256
  int* flags = bsum + 256;                                       // 2

  const int NH = NB * NBLK;                 // 50048
  const int SBH = (NH + 255) / 256;         // 196

  k_detect<<<1, 64, 0, stream>>>((const unsigned short*)feat,
                                 (const unsigned int*)eidx, flags);
  k_hist1<<<NBLK, 256, 0, stream>>>(eidx, flags, hist);
  k_scan1<<<SBH, 256, 0, stream>>>(hist, hscan, bsum, NH);
  k_scan2<<<1, 256, 0, stream>>>(bsum, SBH);
  k_scan3<<<SBH, 256, 0, stream>>>(hscan, bsum, NH);
  k_scatter<<<NBLK, 256, 0, stream>>>(eidx, flags, hscan, ebuf);
  k_place<<<NB, 256, 0, stream>>>(ebuf, hscan, rowp, csr);

  const int GB = (NTILES + 3) / 4;  // 782 blocks x 4 waves, 1 tile/wave

  const void* xcur = feat;
  int x_raw = 1;
  float* nxt = bufA;
  float* other = bufB;
  for (int i = 0; i < 8; ++i) {
    const void* Wb = (i < 4) ? d_in[2] : d_in[5];
    const void* ab = (i < 4) ? d_in[3] : d_in[6];
    const void* db = (i < 4) ? d_in[4] : d_in[7];
    int head = i & 3;
    k_gemm<<<GB, 256, 0, stream>>>(xcur, x_raw, Wb, ab, db, head, flags,
                                   hb, ssrc, sdst);
    int elu = (i == 3 || i == 7) ? 1 : 0;
    int fin = (i == 7) ? 1 : 0;
    k_agg<<<N_NODES / 4, 256, 0, stream>>>(hb, ssrc, sdst, rowp, csr, nxt,
                                           d_out, flags, elu, fin);
    xcur = nxt; x_raw = 0;
    float* t = nxt; nxt = other; other = t;
  }
}